// Round 15
// baseline (323.065 us; speedup 1.0000x reference)
//
#include <hip/hip_runtime.h>
#include <math.h>

// Sizes fixed by the reference: B=512, T=1024, D_IN=D_OUT=64, H=256.
#define HDIM 256
#define DDIM 64
#define BROWS 512
#define TSTEPS 1024
// Augmented rows: 65 weight rows (t-row + 64 state rows) + 1 bias row.
#define AROWS 66

typedef float f32x2 __attribute__((ext_vector_type(2)));
typedef int   i32x2 __attribute__((ext_vector_type(2)));

// ---- Setup: compose the linear MLP into one 66x64 affine map ----
__global__ void compose1(const float* __restrict__ W0, const float* __restrict__ b0,
                         const float* __restrict__ W1, const float* __restrict__ b1,
                         float* __restrict__ out1) {
    int r = blockIdx.x;    // 0..65
    int c = threadIdx.x;   // 0..255
    const float* arow = (r < 65) ? (W0 + r * HDIM) : b0;
    float acc = (r == 65) ? b1[c] : 0.0f;
    for (int h = 0; h < HDIM; ++h)
        acc = fmaf(arow[h], W1[h * HDIM + c], acc);
    out1[r * HDIM + c] = acc;
}

__global__ void compose2(const float* __restrict__ in1,
                         const float* __restrict__ W2, const float* __restrict__ b2,
                         float* __restrict__ out2) {
    int r = blockIdx.x, c = threadIdx.x;
    const float* arow = in1 + r * HDIM;
    float acc = (r == 65) ? b2[c] : 0.0f;
    for (int h = 0; h < HDIM; ++h)
        acc = fmaf(arow[h], W2[h * HDIM + c], acc);
    out2[r * HDIM + c] = acc;
}

__global__ void compose3(const float* __restrict__ in2,
                         const float* __restrict__ W3, const float* __restrict__ b3,
                         float* __restrict__ out3) {
    int r = blockIdx.x, c = threadIdx.x;   // c 0..63
    const float* arow = in2 + r * HDIM;
    float acc = (r == 65) ? b3[c] : 0.0f;
    for (int h = 0; h < HDIM; ++h)
        acc = fmaf(arow[h], W3[h * DDIM + c], acc);
    out3[r * DDIM + c] = acc;
}

// Packed 2xf32 FMA: acc.lo += a.lo*b.lo; acc.hi += a.hi*b.hi  (VOP3P, CDNA)
__device__ __forceinline__ void pkfma(f32x2& acc, f32x2 a, f32x2 b) {
    asm("v_pk_fma_f32 %0, %1, %2, %0" : "+v"(acc) : "v"(a), "v"(b));
}

// DPP controls (HW-verified by r8/r14 calibration passes)
#define DPP_QP_XOR1 0xB1          // quad_perm [1,0,3,2]  -> lane ^ 1
#define DPP_QP_XOR2 0x4E          // quad_perm [2,3,0,1]  -> lane ^ 2
#define DPP_ROW_MIRROR 0x140      // lane ^ 15 (within row of 16)
#define DPP_ROW_HALF_MIRROR 0x141 // lane ^ 7  (within half-row of 8)

template <int CTRL>
__device__ __forceinline__ unsigned dpp_mov(unsigned v) {
    return (unsigned)__builtin_amdgcn_update_dpp(0, (int)v, CTRL, 0xF, 0xF, true);
}

// Intra-16 butterfly: from per-lane v, materialize the 16 values of v held
// by the 16 lanes of my row (masks {1,2,7,15} xor-span 0..15). 15 movs.
__device__ __forceinline__ void gather16(unsigned v, unsigned bq[16]) {
    bq[0] = v;
    bq[1] = dpp_mov<DPP_QP_XOR1>(bq[0]);
    bq[2] = dpp_mov<DPP_QP_XOR2>(bq[0]);
    bq[3] = dpp_mov<DPP_QP_XOR2>(bq[1]);
#pragma unroll
    for (int i = 0; i < 4; ++i) bq[4 + i] = dpp_mov<DPP_ROW_HALF_MIRROR>(bq[i]);
#pragma unroll
    for (int i = 0; i < 8; ++i) bq[8 + i] = dpp_mov<DPP_ROW_MIRROR>(bq[i]);
}

// ---- Main scan: one wave per batch row, lane = output dim ----
//
// r14 lesson: the LDS write->read round-trip (~215 cyc) was the biggest
// chain block. r14's half-split makes the needed gather INTRA-32-LANE, so
// this round replaces LDS entirely with a register-file butterfly:
// 15 DPP movs -> 16 values, then 16 permlane16_swap -> 16 PRE-PACKED f32x2
// pairs covering all 32 values of my half (the builtin returns a reg pair
// — zero packing cost). Calibration (probe with lane id) maps pair
// elements to source lanes; W is pre-permuted to match (r8/r14-proven).
// Also: broadcast r = rcp(exp2(s)+1) instead of tanh, folding th = 1-2r
// into weights (W2s = -2*K2L*W, C_d = K2L*colsum): the th-fma leaves the
// chain, and y-update y = fma(-2f, r, y+f) is fully off-chain.
// Loop DS: ONE ds_read_b64 (param prefetch). One global store, never waited.
__launch_bounds__(64, 1)
__global__ void fode_scan(const float* __restrict__ x, const float* __restrict__ t,
                          const float* __restrict__ Weff,   // 66 x 64 composed
                          float* __restrict__ out) {
    const int b = blockIdx.x;
    const int d = threadIdx.x;   // 0..63

    __shared__ __align__(8) float2 plds[TSTEPS];  // (dt_k, factor_k); last unused

    const float invG = 0.56418958354775628695f;   // 1/Gamma(0.5)
    const float K2L = 2.88539008177792681472f;    // 2*log2(e)

    // Per-step params (dt, factor): coalesced staging, once per block.
    for (int i = d; i < TSTEPS - 1; i += DDIM) {
        float t0 = t[i];
        float t1 = t[i + 1];
        float dt = t1 - t0;
        plds[i] = make_float2(dt, sqrtf(dt) * invG);
    }

    const int lo = d & 31;
    const int hh = d >> 5;            // my half (0: j=0..31, 1: j=32..63)

    // Calibrate the pair network: probe with lane id. Pair c = (sx[c], sy[c])
    // source lanes (all within my 32-half; network is intra-32).
    int sx[16], sy[16];
    {
        unsigned bq[16];
        gather16((unsigned)d, bq);
#pragma unroll
        for (int i = 0; i < 16; ++i) {
            i32x2 s = __builtin_amdgcn_permlane16_swap((int)bq[i], (int)bq[i],
                                                       false, false);
            sx[i] = s.x;
            sy[i] = s.y;
        }
    }

    // Weight pairs, matched to the calibrated gather order, PRE-FOLDED:
    // W2s[j][col] = -2*K2L*Weff[(1+j)*64+col].
    // WaP: column lo; WbP: column lo+32. (j = source lane, in my half.)
    f32x2 WaP[16], WbP[16];
#pragma unroll
    for (int c = 0; c < 16; ++c) {
        WaP[c].x = -2.0f * K2L * Weff[(1 + sx[c]) * DDIM + lo];
        WaP[c].y = -2.0f * K2L * Weff[(1 + sy[c]) * DDIM + lo];
        WbP[c].x = -2.0f * K2L * Weff[(1 + sx[c]) * DDIM + lo + 32];
        WbP[c].y = -2.0f * K2L * Weff[(1 + sy[c]) * DDIM + lo + 32];
    }
    const float wts   = K2L * Weff[d];             // scaled t-coefficient (col d)
    const float biass = K2L * Weff[65 * DDIM + d]; // scaled folded bias   (col d)
    float Cd = 0.0f;                               // K2L * colsum (col d)
    for (int j = 0; j < DDIM; ++j) Cd += Weff[(1 + j) * DDIM + d];
    Cd *= K2L;

    // Calibrate permlane32_swap for the half-combine (r14-proven).
    auto cal = __builtin_amdgcn_permlane32_swap(d, d, false, false);
    const bool pick0 = (cal[0] == (d ^ 32));

    const unsigned pbase = (unsigned)(uintptr_t)&plds[0];
    const float t0g = t[0];

    float y = x[b * DDIM + d];
    float* op = out + (size_t)b * TSTEPS * DDIM + d;
    *op = y;                                      // solution[:,0,:] = x

    // Gather + 32 pkfma + half-combine: dot = W2s @ v  (for column d)
#define DOT32(VIN, DOTOUT)                                                   \
    {                                                                        \
        unsigned bq[16];                                                     \
        gather16(__float_as_uint(VIN), bq);                                  \
        f32x2 P[16];                                                         \
        _Pragma("unroll")                                                    \
        for (int i = 0; i < 16; ++i) {                                       \
            i32x2 sw_ = __builtin_amdgcn_permlane16_swap((int)bq[i],         \
                                                    (int)bq[i], false, false);\
            P[i].x = __int_as_float(sw_.x);                                  \
            P[i].y = __int_as_float(sw_.y);                                  \
        }                                                                    \
        f32x2 accA0 = {0.f, 0.f}, accA1 = {0.f, 0.f};                        \
        f32x2 accB0 = {0.f, 0.f}, accB1 = {0.f, 0.f};                        \
        _Pragma("unroll")                                                    \
        for (int c = 0; c < 16; c += 2) {                                    \
            pkfma(accA0, P[c], WaP[c]);                                      \
            pkfma(accB0, P[c], WbP[c]);                                      \
            pkfma(accA1, P[c + 1], WaP[c + 1]);                              \
            pkfma(accB1, P[c + 1], WbP[c + 1]);                              \
        }                                                                    \
        f32x2 ra = accA0 + accA1;                                            \
        f32x2 rb = accB0 + accB1;                                            \
        float qa = ra.x + ra.y;                                              \
        float qb = rb.x + rb.y;                                              \
        float keep = (d < 32) ? qa : qb;                                     \
        float send = (d < 32) ? qb : qa;                                     \
        auto sw2 = __builtin_amdgcn_permlane32_swap(__float_as_int(send),    \
                                               __float_as_int(send), false, false);\
        float recv = __int_as_float(pick0 ? sw2[0] : sw2[1]);                \
        DOTOUT = keep + recv;                                                \
    }

    // ---- peel: s_0 = biass + t_0*wts + K2L*(W @ y_0); K2L*W = -W2s/2 ----
    float s;
    {
        // staging writes must land before any plds read below
        asm volatile("s_waitcnt lgkmcnt(0)" ::: "memory");
        float dotY;
        DOT32(y, dotY);
        s = fmaf(-0.5f, dotY, fmaf(t0g, wts, biass));
    }

    f32x2 prm;                                    // (dt_k, f_k)
    prm.x = plds[0].x;
    prm.y = plds[0].y;

    for (int k = 0; k < TSTEPS - 1; ++k) {
        // param prefetch (only DS op in the loop; off-chain)
        f32x2 prmn;
        unsigned paddr = pbase + 8u * (unsigned)(k + 1);
        asm volatile("ds_read_b64 %0, %1" : "=&v"(prmn) : "v"(paddr));

        // off-chain precompute from current prm + s
        float dt = prm.x, f = prm.y;
        float sc  = fmaf(f, Cd, fmaf(dt, wts, s));  // s + dt*wts + f*Cd
        float yf  = y + f;
        float m2f = -2.0f * f;

        // ---- chain: r = rcp(exp2(s)+1) ----
        float e = __builtin_amdgcn_exp2f(s);        // s pre-scaled by 2*log2(e)
        float r = __builtin_amdgcn_rcpf(e + 1.0f);

        float dotT;
        DOT32(r, dotT);
        s = fmaf(f, dotT, sc);                      // s_{k+1}

        // off-chain: y_{k+1} = y + f*(1-2r), fire-and-forget store
        y = fmaf(m2f, r, yf);
        op += DDIM;
        *op = y;

        asm volatile("s_waitcnt lgkmcnt(0)" ::: "memory");  // prmn arrived
        prm = prmn;
    }
#undef DOT32
}

extern "C" void kernel_launch(void* const* d_in, const int* in_sizes, int n_in,
                              void* d_out, int out_size, void* d_ws, size_t ws_size,
                              hipStream_t stream) {
    const float* x  = (const float*)d_in[0];
    const float* t  = (const float*)d_in[1];
    const float* W0 = (const float*)d_in[2];
    const float* b0 = (const float*)d_in[3];
    const float* W1 = (const float*)d_in[4];
    const float* b1 = (const float*)d_in[5];
    const float* W2 = (const float*)d_in[6];
    const float* b2 = (const float*)d_in[7];
    const float* W3 = (const float*)d_in[8];
    const float* b3 = (const float*)d_in[9];
    float* out = (float*)d_out;

    float* buf1 = (float*)d_ws;            // 66*256 floats
    float* buf2 = buf1 + AROWS * HDIM;     // 66*256 floats
    float* buf3 = buf2 + AROWS * HDIM;     // 66*64 floats

    compose1<<<AROWS, HDIM, 0, stream>>>(W0, b0, W1, b1, buf1);
    compose2<<<AROWS, HDIM, 0, stream>>>(buf1, W2, b2, buf2);
    compose3<<<AROWS, DDIM, 0, stream>>>(buf2, W3, b3, buf3);
    fode_scan<<<BROWS, DDIM, 0, stream>>>(x, t, buf3, out);
}